// Round 3
// baseline (208.181 us; speedup 1.0000x reference)
//
#include <hip/hip_runtime.h>
#include <cmath>

namespace {
constexpr float kE   = 3130.0f;
constexpr float kNu  = 0.37f;
constexpr float kSy0 = 64.8f;
constexpr float kH   = 100.0f;
constexpr float kG   = kE / (2.0f * (1.0f + kNu));
constexpr float kLam = kE * kNu / ((1.0f + kNu) * (1.0f - 2.0f * kNu));
constexpr float kC   = kE / ((1.0f + kNu) * (1.0f - 2.0f * kNu));
constexpr float kC11 = kC * (1.0f - kNu);
constexpr float kC12 = kC * kNu;
constexpr float kC2  = 3.0f * kG / (3.0f * kG + kH);  // 3G/(3G+H)
constexpr float kC3  = kH / (3.0f * kG + kH);         // 1 - kC2
constexpr int kS  = 2048;
constexpr int kT  = 16;
constexpr int kNB = kS / kT;   // 128 blocks
constexpr int kLs = 192;
constexpr float kSq15  = 1.224744871391589f;  // sqrt(1.5)
constexpr float kSq3   = 1.732050807568877f;  // sqrt(3)
constexpr float kISq15 = 1.0f / kSq15;
constexpr float kISq3  = 1.0f / kSq3;
}

template<int CTRL, int RM, int BM>
__device__ __forceinline__ float dppmov(float v) {
    return __int_as_float(
        __builtin_amdgcn_update_dpp(0, __float_as_int(v), CTRL, RM, BM, false));
}
// wave64 sum, result in lane 63
__device__ __forceinline__ float wave_sum63(float v) {
    v += dppmov<0x111, 0xf, 0xf>(v);
    v += dppmov<0x112, 0xf, 0xf>(v);
    v += dppmov<0x114, 0xf, 0xf>(v);
    v += dppmov<0x118, 0xf, 0xf>(v);
    v += dppmov<0x142, 0xa, 0xf>(v);
    v += dppmov<0x143, 0xc, 0xf>(v);
    return v;
}

// 5 waves: w0 = deviatoric scan; w1,w2 = strain projection (half-blocks);
// w3,w4 = output einsum + DPP reduce + store (half-blocks).
// Mean stress p(t) = mv . x(t) is purely elastic -> handled by out-waves only.
__global__ __launch_bounds__(320, 1)
void j2_pc5_kernel(const float* __restrict__ x,
                   const float* __restrict__ W1,
                   const float* __restrict__ W2,
                   float* __restrict__ out)
{
    __shared__ float4 ubuf[2][kT][64];   // (du0, du1, dush, duz), sqrt-folded
    __shared__ float4 sgbuf[2][kT][64];  // (s0, s1, s2, -) post-fac deviatoric

    const int b = blockIdx.x;
    const int w = threadIdx.x >> 6;   // 0..4
    const int k = threadIdx.x & 63;

    const float* xb = x + (size_t)b * (kS * 3);
    float* ob = out + (size_t)b * (kS * 3);

    // ---- per-role constants -------------------------------------------------
    float e0[3], e1[3], e2s[3], lv[3];   // u-prod rows (e2s: sqrt3*G folded)
    float spp[3][3], so[3], mv[3];       // out-wave weights
    if (w >= 1) {
        float wr[3][3];
#pragma unroll
        for (int j = 0; j < 3; ++j)
#pragma unroll
            for (int f = 0; f < 3; ++f)
                wr[j][f] = W1[(3 * k + j) * 3 + f];
#pragma unroll
        for (int f = 0; f < 3; ++f) {
            e0[f]  = kC11 * wr[0][f] + kC12 * wr[1][f];
            e1[f]  = kC12 * wr[0][f] + kC11 * wr[1][f];
            e2s[f] = kSq3 * kG * wr[2][f];
            lv[f]  = kLam * (wr[0][f] + wr[1][f]);
            mv[f]  = (e0[f] + e1[f] + lv[f]) * (1.0f / 3.0f);
        }
#pragma unroll
        for (int o = 0; o < 3; ++o) {
            float a0 = log1pf(expf(W2[o * kLs + 3 * k + 0]));
            float a1 = log1pf(expf(W2[o * kLs + 3 * k + 1]));
            float a2 = log1pf(expf(W2[o * kLs + 3 * k + 2]));
            spp[o][0] = a0 * kISq15;
            spp[o][1] = a1 * kISq15;
            spp[o][2] = a2 * kISq3;
            so[o] = a0 + a1;
        }
    }

    // ---- u-prod x-register pipeline (block 0 prologue) ---------------------
    float xv[28];
    if (w == 1) {
        xv[0] = xv[1] = xv[2] = xv[3] = 0.f;      // x_{-1} = 0
        const float4* s4 = reinterpret_cast<const float4*>(xb);
#pragma unroll
        for (int i = 0; i < 6; ++i) {
            float4 v = s4[i];
            xv[4 + 4 * i] = v.x; xv[5 + 4 * i] = v.y;
            xv[6 + 4 * i] = v.z; xv[7 + 4 * i] = v.w;
        }
    } else if (w == 2) {
        const float4* s4 = reinterpret_cast<const float4*>(xb + 20);
#pragma unroll
        for (int i = 0; i < 7; ++i) {
            float4 v = s4[i];
            xv[4 * i]     = v.x; xv[4 * i + 1] = v.y;
            xv[4 * i + 2] = v.z; xv[4 * i + 3] = v.w;
        }
    }

    // ---- scan state ---------------------------------------------------------
    float s0 = 0.f, s1 = 0.f, s2 = 0.f, sz = 0.f;
    float y = kSy0, c2y = kC2 * kSy0;

    // phase p: w1/w2 produce ubuf[block p]; w0 scans block p-1;
    //          w3/w4 emit output for block p-2.
    for (int phase = 0; phase <= kNB + 1; ++phase) {
        if (w == 0) {
            if (phase >= 1 && phase <= kNB) {
                const int blk = phase - 1, rb = blk & 1;
                float4 u[kT];
#pragma unroll
                for (int t = 0; t < kT; ++t) u[t] = ubuf[rb][t][k];
#pragma unroll
                for (int t = 0; t < kT; ++t) {
                    const float s0t = s0 + u[t].x;
                    const float s1t = s1 + u[t].y;
                    const float s2t = s2 + u[t].z;
                    const float szt = sz + u[t].w;
                    const float q2 = fmaf(s0t, s0t, fmaf(s1t, s1t, 1e-12f))
                                   + fmaf(s2t, s2t, szt * szt);
                    const float rq  = __builtin_amdgcn_rsqf(q2);
                    const float fac = fminf(fmaf(c2y, rq, kC3), 1.0f);
                    s0 = fac * s0t; s1 = fac * s1t;
                    s2 = fac * s2t; sz = fac * szt;
                    const float qv = q2 * rq;                 // ~|s_tr|
                    y = fmaf(kC3, fmaxf(qv - y, 0.0f), y);
                    c2y = kC2 * y;
                    sgbuf[rb][t][k] = make_float4(s0, s1, s2, 0.f);
                }
            }
        } else if (w <= 2) {
            if (phase < kNB) {
                const int p = phase, pb = p & 1;
                float xn[28];
                const bool pref = (p + 1 < kNB);
                if (pref) {   // prefetch next block's window (hidden 1 phase)
                    const float4* s4 = reinterpret_cast<const float4*>(
                        xb + (p + 1) * 48 + ((w == 1) ? -4 : 20));
#pragma unroll
                    for (int i = 0; i < 7; ++i) {
                        float4 v = s4[i];
                        xn[4 * i]     = v.x; xn[4 * i + 1] = v.y;
                        xn[4 * i + 2] = v.z; xn[4 * i + 3] = v.w;
                    }
                }
                const int tbase = (w == 2) ? 8 : 0;
#pragma unroll
                for (int t = 0; t < 8; ++t) {
                    const float dx0 = xv[3 * t + 4] - xv[3 * t + 1];
                    const float dx1 = xv[3 * t + 5] - xv[3 * t + 2];
                    const float dx2 = xv[3 * t + 6] - xv[3 * t + 3];
                    const float ux  = fmaf(e0[0], dx0, fmaf(e0[1], dx1, e0[2] * dx2));
                    const float uy  = fmaf(e1[0], dx0, fmaf(e1[1], dx1, e1[2] * dx2));
                    const float ush = fmaf(e2s[0], dx0, fmaf(e2s[1], dx1, e2s[2] * dx2));
                    const float uzl = fmaf(lv[0], dx0, fmaf(lv[1], dx1, lv[2] * dx2));
                    const float um  = (ux + uy + uzl) * (1.0f / 3.0f);
                    ubuf[pb][tbase + t][k] =
                        make_float4(kSq15 * (ux - um), kSq15 * (uy - um),
                                    ush, kSq15 * (uzl - um));
                }
                if (pref) {
#pragma unroll
                    for (int i = 0; i < 28; ++i) xv[i] = xn[i];
                }
            }
        } else {
            if (phase >= 2) {
                const int q = phase - 2, qb = q & 1;
                const int tbase = (w == 4) ? 8 : 0;
                // x for the elastic mean-stress term (L1/L2-hot broadcast)
                float xq[24];
                const float4* s4 = reinterpret_cast<const float4*>(
                    xb + q * 48 + tbase * 3);
#pragma unroll
                for (int i = 0; i < 6; ++i) {
                    float4 v = s4[i];
                    xq[4 * i]     = v.x; xq[4 * i + 1] = v.y;
                    xq[4 * i + 2] = v.z; xq[4 * i + 3] = v.w;
                }
                float r[24];
#pragma unroll
                for (int t = 0; t < 8; ++t) {
                    float4 s = sgbuf[qb][tbase + t][k];
                    const float pm = fmaf(mv[0], xq[3 * t + 0],
                                     fmaf(mv[1], xq[3 * t + 1],
                                          mv[2] * xq[3 * t + 2]));
#pragma unroll
                    for (int o = 0; o < 3; ++o) {
                        const float A = fmaf(spp[o][0], s.x,
                                        fmaf(spp[o][1], s.y, spp[o][2] * s.z));
                        r[3 * t + o] = fmaf(pm, so[o], A);
                    }
                }
#pragma unroll
                for (int v = 0; v < 24; ++v) r[v] = wave_sum63(r[v]);
                if (k == 63) {
                    float4* o4 = reinterpret_cast<float4*>(ob + q * 48 + tbase * 3);
#pragma unroll
                    for (int i = 0; i < 6; ++i)
                        o4[i] = make_float4(r[4 * i], r[4 * i + 1],
                                            r[4 * i + 2], r[4 * i + 3]);
                }
            }
        }
        __syncthreads();
    }
}

extern "C" void kernel_launch(void* const* d_in, const int* in_sizes, int n_in,
                              void* d_out, int out_size, void* d_ws, size_t ws_size,
                              hipStream_t stream) {
    const float* x  = (const float*)d_in[0];   // (128, 2048, 3)
    const float* W1 = (const float*)d_in[1];   // (192, 3)
    const float* W2 = (const float*)d_in[2];   // (3, 192)
    float* out = (float*)d_out;                // (128, 2048, 3)

    j2_pc5_kernel<<<dim3(128), dim3(320), 0, stream>>>(x, W1, W2, out);
}